// Round 1
// baseline (7996.294 us; speedup 1.0000x reference)
//
#include <hip/hip_runtime.h>

// Problem constants
#define B_  128
#define T_  512
#define I_  512
#define H_  1024
#define G4  4096   // 4*H

typedef __attribute__((ext_vector_type(8))) short   short8;
typedef __attribute__((ext_vector_type(4))) short   short4v;
typedef __attribute__((ext_vector_type(4))) float   f32x4;

__device__ __forceinline__ float bf2f(short u){
  return __uint_as_float(((unsigned)(unsigned short)u) << 16);
}
__device__ __forceinline__ short f2bf(float f){
  unsigned u = __float_as_uint(f);
  unsigned r = (u + 0x7FFFu + ((u >> 16) & 1u)) >> 16;  // RNE
  return (short)r;
}
__device__ __forceinline__ float sigm(float x){ return 1.0f/(1.0f + __expf(-x)); }
__device__ __forceinline__ float tanh_(float x){ return 1.0f - 2.0f/(__expf(2.0f*x) + 1.0f); }

// ---------------- fp32 -> bf16 elementwise convert (vectorized x4) ----------------
__global__ __launch_bounds__(256) void cvt_bf16(const float* __restrict__ in,
                                                short* __restrict__ out, int nq){
  int i = blockIdx.x*256 + threadIdx.x;
  if (i >= nq) return;
  float4 v = ((const float4*)in)[i];
  short4v o; o.x = f2bf(v.x); o.y = f2bf(v.y); o.z = f2bf(v.z); o.w = f2bf(v.w);
  ((short4v*)out)[i] = o;
}

// ---------------- W_hh fp32 [4096][1024] -> bf16 MFMA-fragment-swizzled ----------------
// out chunk index c = ((g*64 + jf)*32 + s)*64 + l ; chunk = 8 bf16 (16B)
// represents W[g*1024 + jf*16 + (l&15)][s*32 + (l>>4)*8 + e]
__global__ __launch_bounds__(256) void swz_whh(const float* __restrict__ W,
                                               short* __restrict__ out){
  int c = blockIdx.x*256 + threadIdx.x;      // 0 .. 524287
  int l = c & 63, s = (c >> 6) & 31, jf = (c >> 11) & 63, g = c >> 17;
  long row = (long)(g*1024 + jf*16 + (l & 15));
  int col = s*32 + (l >> 4)*8;
  const float* src = W + row*H_ + col;
  short8 o;
#pragma unroll
  for (int e = 0; e < 8; ++e) o[e] = f2bf(src[e]);
  ((short8*)out)[c] = o;
}

// ---------------- projection GEMM: C[m,n] = sum_k A[m,k]*W[n,k] + bih[n]+bhh[n] ----------------
// A: [M,K] bf16 row-major (M = B*T, rows m = b*T+t), W: [4096,K] bf16 row-major,
// C: [M,4096] bf16. Tiles 128x128, BK=32, 256 thr (4 waves 2x2, 64x64/wave).
template<int K>
__global__ __launch_bounds__(256) void proj_gemm(const short* __restrict__ A,
                                                 const short* __restrict__ W,
                                                 const float* __restrict__ bih,
                                                 const float* __restrict__ bhh,
                                                 short* __restrict__ C){
  __shared__ short lds[2][2][128*40];  // [buf][A/B][row*40+col], pad 40 kills conflicts
  const int tid = threadIdx.x;
  const int l  = tid & 63, wv = tid >> 6;
  const int wm = wv >> 1,  wn = wv & 1;
  const int nt = blockIdx.x, mt = blockIdx.y;
  const int r0 = tid >> 2, cb = (tid & 3) * 8;
  const short* Ab = A + (long)(mt*128 + r0)*K + cb;
  const short* Wb = W + (long)(nt*128 + r0)*K + cb;
  const int lo  = r0*40 + cb;
  const int lo2 = lo + 64*40;
  const int NK = K/32;

  short8 pa0 = *(const short8*)(Ab);
  short8 pa1 = *(const short8*)(Ab + 64*K);
  short8 pb0 = *(const short8*)(Wb);
  short8 pb1 = *(const short8*)(Wb + 64*K);
  *(short8*)&lds[0][0][lo]  = pa0;
  *(short8*)&lds[0][0][lo2] = pa1;
  *(short8*)&lds[0][1][lo]  = pb0;
  *(short8*)&lds[0][1][lo2] = pb1;

  f32x4 acc[4][4];
  f32x4 z = {0.f,0.f,0.f,0.f};
#pragma unroll
  for (int i = 0; i < 4; ++i)
#pragma unroll
    for (int j = 0; j < 4; ++j) acc[i][j] = z;

  for (int kt = 0; kt < NK; ++kt){
    __syncthreads();
    if (kt + 1 < NK){
      pa0 = *(const short8*)(Ab + (kt+1)*32);
      pa1 = *(const short8*)(Ab + (kt+1)*32 + 64*K);
      pb0 = *(const short8*)(Wb + (kt+1)*32);
      pb1 = *(const short8*)(Wb + (kt+1)*32 + 64*K);
    }
    const short* As = lds[kt & 1][0];
    const short* Bs = lds[kt & 1][1];
    short8 bfr[4];
#pragma unroll
    for (int nf = 0; nf < 4; ++nf)
      bfr[nf] = *(const short8*)&Bs[(wn*64 + nf*16 + (l & 15))*40 + (l >> 4)*8];
#pragma unroll
    for (int mf = 0; mf < 4; ++mf){
      short8 af = *(const short8*)&As[(wm*64 + mf*16 + (l & 15))*40 + (l >> 4)*8];
#pragma unroll
      for (int nf = 0; nf < 4; ++nf)
        acc[mf][nf] = __builtin_amdgcn_mfma_f32_16x16x32_bf16(af, bfr[nf], acc[mf][nf], 0, 0, 0);
    }
    if (kt + 1 < NK){
      int nb = (kt + 1) & 1;
      *(short8*)&lds[nb][0][lo]  = pa0;
      *(short8*)&lds[nb][0][lo2] = pa1;
      *(short8*)&lds[nb][1][lo]  = pb0;
      *(short8*)&lds[nb][1][lo2] = pb1;
    }
  }

  const int mrow0 = mt*128 + wm*64;
  const int ncol0 = nt*128 + wn*64;
#pragma unroll
  for (int nf = 0; nf < 4; ++nf){
    int n = ncol0 + nf*16 + (l & 15);
    float bs = bih[n] + bhh[n];
#pragma unroll
    for (int mf = 0; mf < 4; ++mf){
#pragma unroll
      for (int r = 0; r < 4; ++r){
        int m = mrow0 + mf*16 + (l >> 4)*4 + r;   // C/D: row=(l>>4)*4+r, col=l&15
        C[(long)m*G4 + n] = f2bf(acc[mf][nf][r] + bs);
      }
    }
  }
}

// ---------------- one LSTM timestep (fused gates GEMM + elementwise) ----------------
// grid: (jf=64, bt=8), block 256 (4 waves). Each block owns [16 b x 16 j x 4 gates],
// waves split K=1024 into 4x256, LDS-reduce, then 1 thread per (b,j) elementwise.
// h carried in MFMA A-fragment layout: chunk ((b>>4)*32 + s)*64 + (kq*16 + (b&15)),
// elem e  <->  h[b][s*32 + kq*8 + e]  (bf16).
template<int LAYER>
__global__ __launch_bounds__(256) void lstm_step(
    const short* __restrict__ hcur, short* __restrict__ hnext,
    const short* __restrict__ Wsw, const short* __restrict__ xg,
    float* __restrict__ cbuf,
    const float* __restrict__ om, const float* __restrict__ hm, const float* __restrict__ cm,
    short* __restrict__ out0, float* __restrict__ dout, int t)
{
  const int tid = threadIdx.x;
  const int l = tid & 63, wv = tid >> 6;
  const int jf = blockIdx.x, bt = blockIdx.y;

  const short8* hp = (const short8*)hcur + (bt*32 + wv*8)*64 + l;
  short8 a[8];
#pragma unroll
  for (int ks = 0; ks < 8; ++ks) a[ks] = hp[ks*64];

  f32x4 acc[4];
  f32x4 z = {0.f,0.f,0.f,0.f};
#pragma unroll
  for (int g = 0; g < 4; ++g) acc[g] = z;

#pragma unroll
  for (int g = 0; g < 4; ++g){
    const short8* wp = (const short8*)Wsw + ((g*64 + jf)*32 + wv*8)*64 + l;
#pragma unroll
    for (int ks = 0; ks < 8; ++ks)
      acc[g] = __builtin_amdgcn_mfma_f32_16x16x32_bf16(a[ks], wp[ks*64], acc[g], 0, 0, 0);
  }

  __shared__ float red[16][256];   // [g*4+r][wave*64 + lane] — store conflict-free
#pragma unroll
  for (int g = 0; g < 4; ++g)
#pragma unroll
    for (int r = 0; r < 4; ++r)
      red[g*4 + r][tid] = acc[g][r];
  __syncthreads();

  const int bl = tid >> 4, jl = tid & 15;
  const int b = bt*16 + bl;
  const int jcol = jf*16 + jl;
  const int lsrc = ((bl >> 2) << 4) | jl;   // lane that holds row bl, col jl
  const int rr = bl & 3;                    // its reg index

  float gate[4];
#pragma unroll
  for (int g = 0; g < 4; ++g){
    float s = red[g*4+rr][lsrc] + red[g*4+rr][64+lsrc]
            + red[g*4+rr][128+lsrc] + red[g*4+rr][192+lsrc];
    gate[g] = s + bf2f(xg[((long)b*T_ + t)*G4 + g*H_ + jcol]);
  }
  float ii = sigm(gate[0]);
  float ff = sigm(gate[1]);
  float gg = tanh_(gate[2]);
  float oo = sigm(gate[3]);

  const long bj = (long)b*H_ + jcol;
  float c2 = ff*cbuf[bj] + ii*gg;
  float h2 = oo*tanh_(c2);
  float cn = c2*cm[bj];
  float hn = h2*hm[bj];
  cbuf[bj] = cn;

  // write h carry in fragment layout for next step's A operand
  int s_ = jcol >> 5, kq = (jcol >> 3) & 3, e = jcol & 7;
  hnext[((bt*32 + s_)*64 + kq*16 + bl)*8 + e] = f2bf(hn);

  float ov = h2*om[bj];
  if (LAYER == 0){
    out0[((long)b*T_ + t)*H_ + jcol] = f2bf(ov);
  } else {
    dout[((long)b*T_ + t)*H_ + jcol] = ov;
    if (t == T_ - 1){
      dout[(long)B_*T_*H_ + bj] = hn;                    // hf
      dout[(long)B_*T_*H_ + (long)B_*H_ + bj] = cn;      // cf
    }
  }
}

extern "C" void kernel_launch(void* const* d_in, const int* in_sizes, int n_in,
                              void* d_out, int out_size, void* d_ws, size_t ws_size,
                              hipStream_t stream){
  const float* x    = (const float*)d_in[0];
  const float* Wih0 = (const float*)d_in[1];
  const float* Whh0 = (const float*)d_in[2];
  const float* bih0 = (const float*)d_in[3];
  const float* bhh0 = (const float*)d_in[4];
  const float* Wih1 = (const float*)d_in[5];
  const float* Whh1 = (const float*)d_in[6];
  const float* bih1 = (const float*)d_in[7];
  const float* bhh1 = (const float*)d_in[8];
  const float* omsk = (const float*)d_in[9];
  const float* hmsk = (const float*)d_in[10];
  const float* cmsk = (const float*)d_in[11];
  float* out = (float*)d_out;

  char* p = (char*)d_ws;
  auto alloc = [&](size_t bytes)->char*{
    char* r = p; p += (bytes + 255) & ~(size_t)255; return r;
  };
  short* xg      = (short*)alloc((size_t)65536*4096*2);   // [b*T+t][4096] bf16 (shared by both layers)
  short* x_bf    = (short*)alloc((size_t)33554432*2);     // x as bf16, [b][t][512]
  short* out0_bf = (short*)alloc((size_t)67108864*2);     // layer-0 outputs, [b][t][1024] bf16
  short* wih0_bf = (short*)alloc((size_t)2097152*2);
  short* wih1_bf = (short*)alloc((size_t)4194304*2);
  short* whh0_sw = (short*)alloc((size_t)4194304*2);
  short* whh1_sw = (short*)alloc((size_t)4194304*2);
  short* hb0     = (short*)alloc((size_t)131072*2);
  short* hb1     = (short*)alloc((size_t)131072*2);
  float* cbuf    = (float*)alloc((size_t)131072*4);
  if ((size_t)(p - (char*)d_ws) > ws_size) return;   // workspace too small — bail

  // converts / weight swizzles
  cvt_bf16<<<33554432/4/256, 256, 0, stream>>>(x,    x_bf,    33554432/4);
  cvt_bf16<<<2097152/4/256,  256, 0, stream>>>(Wih0, wih0_bf, 2097152/4);
  cvt_bf16<<<4194304/4/256,  256, 0, stream>>>(Wih1, wih1_bf, 4194304/4);
  swz_whh <<<524288/256,     256, 0, stream>>>(Whh0, whh0_sw);
  swz_whh <<<524288/256,     256, 0, stream>>>(Whh1, whh1_sw);

  short* hb[2] = {hb0, hb1};

  // ---- layer 0 ----
  proj_gemm<512><<<dim3(32, 512), 256, 0, stream>>>(x_bf, wih0_bf, bih0, bhh0, xg);
  hipMemsetAsync(hb0, 0, 262144, stream);
  hipMemsetAsync(cbuf, 0, 524288, stream);
  for (int t = 0; t < T_; ++t)
    lstm_step<0><<<dim3(64, 8), 256, 0, stream>>>(hb[t & 1], hb[(t + 1) & 1], whh0_sw, xg,
        cbuf, omsk, hmsk, cmsk, out0_bf, nullptr, t);

  // ---- layer 1 ----
  proj_gemm<1024><<<dim3(32, 512), 256, 0, stream>>>(out0_bf, wih1_bf, bih1, bhh1, xg);
  hipMemsetAsync(hb0, 0, 262144, stream);
  hipMemsetAsync(cbuf, 0, 524288, stream);
  for (int t = 0; t < T_; ++t)
    lstm_step<1><<<dim3(64, 8), 256, 0, stream>>>(hb[t & 1], hb[(t + 1) & 1], whh1_sw, xg,
        cbuf, omsk + 131072, hmsk + 131072, cmsk + 131072, nullptr, out, t);
}